// Round 2
// baseline (712.026 us; speedup 1.0000x reference)
//
#include <hip/hip_runtime.h>
#include <hip/hip_bf16.h>

#define N_NODES 50000
#define N_EDGES 800000
#define NODE_DIM 256
#define EDGE_DIM 64
#define HIDDEN 512
#define OUT_DIM 256
#define IN_DIM 320   // EDGE_DIM + NODE_DIM

typedef __bf16 bf16_t;
typedef bf16_t bf16x8 __attribute__((ext_vector_type(8)));
typedef float floatx4 __attribute__((ext_vector_type(4)));

__device__ inline bf16_t to_bf16(float f) {
    __hip_bfloat16 h = __float2bfloat16(f);
    bf16_t b;
    __builtin_memcpy(&b, &h, 2);
    return b;
}

// async 16B global -> LDS (wave-uniform LDS base + lane*16 pattern required)
__device__ inline void async16(const void* g, void* l) {
    __builtin_amdgcn_global_load_lds(
        (const __attribute__((address_space(1))) unsigned int*)g,
        (__attribute__((address_space(3))) unsigned int*)l, 16, 0, 0);
}

// ---------------------------------------------------------------------------
// K1: histogram of target indices (int atomics)
// ---------------------------------------------------------------------------
__global__ __launch_bounds__(256) void hist_counts(
    const int* __restrict__ eidx, int* __restrict__ counts) {
    int e = blockIdx.x * 256 + threadIdx.x;
    if (e >= N_EDGES) return;
    int t = min(max(eidx[N_EDGES + e], 0), N_NODES - 1);
    atomicAdd(&counts[t], 1);
}

// ---------------------------------------------------------------------------
// K2: exclusive prefix sum over counts -> offsets[N+1], cursor copy.
// Single block, 256 threads, 196 elems/thread + Hillis-Steele block scan.
// ---------------------------------------------------------------------------
__global__ __launch_bounds__(256) void scan_offsets(
    const int* __restrict__ counts, int* __restrict__ offsets,
    int* __restrict__ cursor) {
    __shared__ int sums[256];
    const int t = threadIdx.x;
    const int CH = (N_NODES + 255) / 256;  // 196
    const int base = t * CH;
    int s = 0;
    for (int i = 0; i < CH; ++i) {
        int idx = base + i;
        if (idx < N_NODES) s += counts[idx];
    }
    sums[t] = s;
    __syncthreads();
    for (int off = 1; off < 256; off <<= 1) {
        int v = (t >= off) ? sums[t - off] : 0;
        __syncthreads();
        sums[t] += v;
        __syncthreads();
    }
    int run = (t == 0) ? 0 : sums[t - 1];
    for (int i = 0; i < CH; ++i) {
        int idx = base + i;
        if (idx < N_NODES) {
            offsets[idx] = run;
            cursor[idx] = run;
            run += counts[idx];
        }
    }
    if (t == 255) offsets[N_NODES] = sums[255];
}

// ---------------------------------------------------------------------------
// K3: counting-sort pass — place edge ids into per-node contiguous ranges
// ---------------------------------------------------------------------------
__global__ __launch_bounds__(256) void scatter_ids(
    const int* __restrict__ eidx, int* __restrict__ cursor,
    int* __restrict__ sorted) {
    int e = blockIdx.x * 256 + threadIdx.x;
    if (e >= N_EDGES) return;
    int t = min(max(eidx[N_EDGES + e], 0), N_NODES - 1);
    int pos = atomicAdd(&cursor[t], 1);
    sorted[pos] = e;
}

// ---------------------------------------------------------------------------
// K4: gather + mean + concat + bf16 cast -> combined[N, 320]
// One wave per node; lane = edge-feature dim (64 lanes = 64 dims).
// ---------------------------------------------------------------------------
__global__ __launch_bounds__(256) void gather_combined(
    const float* __restrict__ ef, const int* __restrict__ sorted,
    const int* __restrict__ offsets, const float* __restrict__ node,
    bf16_t* __restrict__ combined) {
    int wave = (blockIdx.x * 256 + threadIdx.x) >> 6;
    int lane = threadIdx.x & 63;
    if (wave >= N_NODES) return;
    int beg = offsets[wave], end = offsets[wave + 1];
    float acc = 0.f;
    int j = beg;
    // unroll-by-2 so two edge-row loads are in flight
    for (; j + 1 < end; j += 2) {
        int e0 = sorted[j], e1 = sorted[j + 1];
        float v0 = ef[(size_t)e0 * EDGE_DIM + lane];
        float v1 = ef[(size_t)e1 * EDGE_DIM + lane];
        acc += v0 + v1;
    }
    if (j < end) {
        int e0 = sorted[j];
        acc += ef[(size_t)e0 * EDGE_DIM + lane];
    }
    float inv = 1.0f / (float)max(end - beg, 1);
    size_t cb = (size_t)wave * IN_DIM;
    combined[cb + lane] = to_bf16(acc * inv);
    const float* nf = node + (size_t)wave * NODE_DIM;
#pragma unroll
    for (int c = 0; c < 4; ++c)
        combined[cb + EDGE_DIM + c * 64 + lane] = to_bf16(nf[c * 64 + lane]);
}

// ---------------------------------------------------------------------------
// K5: weights -> transposed bf16
// ---------------------------------------------------------------------------
__global__ __launch_bounds__(256) void convert_weights(
    const float* __restrict__ W1, const float* __restrict__ W2,
    bf16_t* __restrict__ W1T, bf16_t* __restrict__ W2T) {
    int idx = blockIdx.x * 256 + threadIdx.x;
    if (idx < IN_DIM * HIDDEN) {
        int k = idx / HIDDEN, n = idx - k * HIDDEN;
        W1T[(size_t)n * IN_DIM + k] = to_bf16(W1[idx]);
    } else {
        int j = idx - IN_DIM * HIDDEN;
        if (j < HIDDEN * OUT_DIM) {
            int k = j / OUT_DIM, n = j - k * OUT_DIM;
            W2T[(size_t)n * HIDDEN + k] = to_bf16(W2[j]);
        }
    }
}

// ---------------------------------------------------------------------------
// K6/K7: C[M,N] = act(A[M,K] @ BT[N,K]^T + bias), m97 structure:
// unpadded 128x32 LDS tiles staged via global_load_lds width=16.
// 4 waves 2x2, each 4x4 16x16x32 bf16 MFMAs.
// Layouts (verified): A-frag m=lane&15,k=quad*8+j; B-frag n=lane&15;
// C/D col=lane&15, row=quad*4+reg.
// ---------------------------------------------------------------------------
template <bool RELU, bool OUT_BF16>
__global__ __launch_bounds__(256) void gemm_bt(
    const bf16_t* __restrict__ A, const bf16_t* __restrict__ BT,
    const float* __restrict__ bias, void* __restrict__ Cout,
    int M, int N, int K) {
    __shared__ bf16_t As[128][32];  // unpadded: required by global_load_lds
    __shared__ bf16_t Bs[128][32];

    const int tid = threadIdx.x;
    const int lane = tid & 63;
    const int w = tid >> 6;
    const int wm = (w & 1) * 64;
    const int wn = (w >> 1) * 64;
    const int lrow = lane & 15;
    const int quad = lane >> 4;
    const int kq = quad * 8;
    const int m0 = blockIdx.x * 128;
    const int n0 = blockIdx.y * 128;

    floatx4 acc[4][4] = {};

    const int nkt = K / 32;
    for (int kt = 0; kt < nkt; ++kt) {
        const int k0 = kt * 32;
        __syncthreads();
#pragma unroll
        for (int it = 0; it < 2; ++it) {
            int slot = it * 256 + tid;
            int row = slot >> 2;
            int cg = (slot & 3) * 8;
            int gm = min(m0 + row, M - 1);  // clamp; garbage rows masked in epilogue
            async16(&A[(size_t)gm * K + k0 + cg], (bf16_t*)As + slot * 8);
            async16(&BT[(size_t)(n0 + row) * K + k0 + cg], (bf16_t*)Bs + slot * 8);
        }
        __syncthreads();  // drains vmcnt before LDS reads

        bf16x8 af[4], bfr[4];
#pragma unroll
        for (int mi = 0; mi < 4; ++mi)
            af[mi] = *reinterpret_cast<const bf16x8*>(&As[wm + mi * 16 + lrow][kq]);
#pragma unroll
        for (int ni = 0; ni < 4; ++ni)
            bfr[ni] = *reinterpret_cast<const bf16x8*>(&Bs[wn + ni * 16 + lrow][kq]);
#pragma unroll
        for (int mi = 0; mi < 4; ++mi)
#pragma unroll
            for (int ni = 0; ni < 4; ++ni)
                acc[mi][ni] = __builtin_amdgcn_mfma_f32_16x16x32_bf16(
                    af[mi], bfr[ni], acc[mi][ni], 0, 0, 0);
    }

#pragma unroll
    for (int ni = 0; ni < 4; ++ni) {
        int gn = n0 + wn + ni * 16 + lrow;
        float bv = bias[gn];
#pragma unroll
        for (int mi = 0; mi < 4; ++mi) {
            int gmb = m0 + wm + mi * 16 + quad * 4;
#pragma unroll
            for (int r = 0; r < 4; ++r) {
                int gm = gmb + r;
                if (gm < M) {
                    float v = acc[mi][ni][r] + bv;
                    if (RELU) v = fmaxf(v, 0.0f);
                    if (OUT_BF16)
                        ((bf16_t*)Cout)[(size_t)gm * N + gn] = to_bf16(v);
                    else
                        ((float*)Cout)[(size_t)gm * N + gn] = v;
                }
            }
        }
    }
}

// ---------------------------------------------------------------------------
extern "C" void kernel_launch(void* const* d_in, const int* in_sizes, int n_in,
                              void* d_out, int out_size, void* d_ws, size_t ws_size,
                              hipStream_t stream) {
    const float* node = (const float*)d_in[0];
    const int* eidx = (const int*)d_in[1];
    const float* ef = (const float*)d_in[2];
    const float* W1 = (const float*)d_in[3];
    const float* b1 = (const float*)d_in[4];
    const float* W2 = (const float*)d_in[5];
    const float* b2 = (const float*)d_in[6];
    float* out = (float*)d_out;

    char* ws = (char*)d_ws;
    int* counts = (int*)ws;                               //   200,000 B
    int* offsets = (int*)(ws + 200000);                   //   200,004 B
    int* cursor = (int*)(ws + 400016);                    //   200,000 B
    int* sorted = (int*)(ws + 600016);                    // 3,200,000 B
    bf16_t* combined = (bf16_t*)(ws + 3800032);           // 32,000,000 B (16-aligned)
    bf16_t* h = (bf16_t*)(ws + 35800032);                 // 51,200,000 B (16-aligned)
    bf16_t* W1T = (bf16_t*)(ws + 87000032);               //   327,680 B
    bf16_t* W2T = (bf16_t*)(ws + 87327712);               //   262,144 B

    hipMemsetAsync(counts, 0, 200000, stream);  // ws re-poisoned 0xAA each call

    hist_counts<<<(N_EDGES + 255) / 256, 256, 0, stream>>>(eidx, counts);
    scan_offsets<<<1, 256, 0, stream>>>(counts, offsets, cursor);
    scatter_ids<<<(N_EDGES + 255) / 256, 256, 0, stream>>>(eidx, cursor, sorted);
    gather_combined<<<(N_NODES * 64 + 255) / 256, 256, 0, stream>>>(
        ef, sorted, offsets, node, combined);

    convert_weights<<<(IN_DIM * HIDDEN + HIDDEN * OUT_DIM + 255) / 256, 256, 0, stream>>>(
        W1, W2, W1T, W2T);

    // h = relu(combined @ W1 + b1)   [50000,512] bf16
    gemm_bt<true, true><<<dim3((N_NODES + 127) / 128, HIDDEN / 128), 256, 0, stream>>>(
        combined, W1T, b1, (void*)h, N_NODES, HIDDEN, IN_DIM);

    // out = h @ W2 + b2              [50000,256] f32
    gemm_bt<false, false><<<dim3((N_NODES + 127) / 128, OUT_DIM / 128), 256, 0, stream>>>(
        h, W2T, b2, (void*)out, N_NODES, OUT_DIM, HIDDEN);
}

// Round 3
// 579.424 us; speedup vs baseline: 1.2289x; 1.2289x over previous
//
#include <hip/hip_runtime.h>
#include <hip/hip_bf16.h>

#define N_NODES 50000
#define N_EDGES 800000
#define NODE_DIM 256
#define EDGE_DIM 64
#define HIDDEN 512
#define OUT_DIM 256
#define IN_DIM 320   // EDGE_DIM + NODE_DIM
#define SCAN_BLOCKS ((N_NODES + 255) / 256)  // 196

typedef __bf16 bf16_t;
typedef bf16_t bf16x8 __attribute__((ext_vector_type(8)));
typedef float floatx4 __attribute__((ext_vector_type(4)));

__device__ inline bf16_t to_bf16(float f) {
    __hip_bfloat16 h = __float2bfloat16(f);
    bf16_t b;
    __builtin_memcpy(&b, &h, 2);
    return b;
}

// async 16B global -> LDS (wave-uniform LDS base + lane*16 pattern required)
__device__ inline void async16(const void* g, void* l) {
    __builtin_amdgcn_global_load_lds(
        (const __attribute__((address_space(1))) unsigned int*)g,
        (__attribute__((address_space(3))) unsigned int*)l, 16, 0, 0);
}

// ---------------------------------------------------------------------------
// K1: histogram of target indices (int atomics)
// ---------------------------------------------------------------------------
__global__ __launch_bounds__(256) void hist_counts(
    const int* __restrict__ eidx, int* __restrict__ counts) {
    int e = blockIdx.x * 256 + threadIdx.x;
    if (e >= N_EDGES) return;
    int t = min(max(eidx[N_EDGES + e], 0), N_NODES - 1);
    atomicAdd(&counts[t], 1);
}

// ---------------------------------------------------------------------------
// K2a: per-block exclusive scan (256 elems/block), emit block totals
// ---------------------------------------------------------------------------
__global__ __launch_bounds__(256) void scan_blocks(
    const int* __restrict__ counts, int* __restrict__ local_excl,
    int* __restrict__ blocksums) {
    __shared__ int s[256];
    int t = threadIdx.x;
    int idx = blockIdx.x * 256 + t;
    int v = (idx < N_NODES) ? counts[idx] : 0;
    s[t] = v;
    __syncthreads();
#pragma unroll
    for (int off = 1; off < 256; off <<= 1) {
        int u = (t >= off) ? s[t - off] : 0;
        __syncthreads();
        s[t] += u;
        __syncthreads();
    }
    if (idx < N_NODES) local_excl[idx] = s[t] - v;  // exclusive
    if (t == 255) blocksums[blockIdx.x] = s[255];
}

// ---------------------------------------------------------------------------
// K2b: scan the block totals (196 elems, single block, one elem/thread)
// ---------------------------------------------------------------------------
__global__ __launch_bounds__(256) void scan_sums(
    const int* __restrict__ blocksums, int* __restrict__ scanned,
    int* __restrict__ offsets) {
    __shared__ int s[256];
    int t = threadIdx.x;
    int v = (t < SCAN_BLOCKS) ? blocksums[t] : 0;
    s[t] = v;
    __syncthreads();
#pragma unroll
    for (int off = 1; off < 256; off <<= 1) {
        int u = (t >= off) ? s[t - off] : 0;
        __syncthreads();
        s[t] += u;
        __syncthreads();
    }
    if (t < SCAN_BLOCKS) scanned[t] = s[t] - v;  // exclusive
    if (t == 255) offsets[N_NODES] = s[255];     // total = N_EDGES
}

// ---------------------------------------------------------------------------
// K2c: offsets[i] = local_excl[i] + scanned[block]; cursor copy
// ---------------------------------------------------------------------------
__global__ __launch_bounds__(256) void add_base(
    const int* __restrict__ local_excl, const int* __restrict__ scanned,
    int* __restrict__ offsets, int* __restrict__ cursor) {
    int idx = blockIdx.x * 256 + threadIdx.x;
    if (idx >= N_NODES) return;
    int o = local_excl[idx] + scanned[blockIdx.x];
    offsets[idx] = o;
    cursor[idx] = o;
}

// ---------------------------------------------------------------------------
// K3: counting-sort pass — place edge ids into per-node contiguous ranges
// ---------------------------------------------------------------------------
__global__ __launch_bounds__(256) void scatter_ids(
    const int* __restrict__ eidx, int* __restrict__ cursor,
    int* __restrict__ sorted) {
    int e = blockIdx.x * 256 + threadIdx.x;
    if (e >= N_EDGES) return;
    int t = min(max(eidx[N_EDGES + e], 0), N_NODES - 1);
    int pos = atomicAdd(&cursor[t], 1);
    sorted[pos] = e;
}

// ---------------------------------------------------------------------------
// K4: gather + mean + concat + bf16 cast -> combined[N, 320]
// One wave per node; lane = edge-feature dim (64 lanes = 64 dims).
// ---------------------------------------------------------------------------
__global__ __launch_bounds__(256) void gather_combined(
    const float* __restrict__ ef, const int* __restrict__ sorted,
    const int* __restrict__ offsets, const float* __restrict__ node,
    bf16_t* __restrict__ combined) {
    int wave = (blockIdx.x * 256 + threadIdx.x) >> 6;
    int lane = threadIdx.x & 63;
    if (wave >= N_NODES) return;
    int beg = offsets[wave], end = offsets[wave + 1];
    float acc = 0.f;
    int j = beg;
    for (; j + 1 < end; j += 2) {
        int e0 = sorted[j], e1 = sorted[j + 1];
        float v0 = ef[(size_t)e0 * EDGE_DIM + lane];
        float v1 = ef[(size_t)e1 * EDGE_DIM + lane];
        acc += v0 + v1;
    }
    if (j < end) {
        int e0 = sorted[j];
        acc += ef[(size_t)e0 * EDGE_DIM + lane];
    }
    float inv = 1.0f / (float)max(end - beg, 1);
    size_t cb = (size_t)wave * IN_DIM;
    combined[cb + lane] = to_bf16(acc * inv);
    const float* nf = node + (size_t)wave * NODE_DIM;
#pragma unroll
    for (int c = 0; c < 4; ++c)
        combined[cb + EDGE_DIM + c * 64 + lane] = to_bf16(nf[c * 64 + lane]);
}

// ---------------------------------------------------------------------------
// K5: weights -> transposed bf16
// ---------------------------------------------------------------------------
__global__ __launch_bounds__(256) void convert_weights(
    const float* __restrict__ W1, const float* __restrict__ W2,
    bf16_t* __restrict__ W1T, bf16_t* __restrict__ W2T) {
    int idx = blockIdx.x * 256 + threadIdx.x;
    if (idx < IN_DIM * HIDDEN) {
        int k = idx / HIDDEN, n = idx - k * HIDDEN;
        W1T[(size_t)n * IN_DIM + k] = to_bf16(W1[idx]);
    } else {
        int j = idx - IN_DIM * HIDDEN;
        if (j < HIDDEN * OUT_DIM) {
            int k = j / OUT_DIM, n = j - k * OUT_DIM;
            W2T[(size_t)n * HIDDEN + k] = to_bf16(W2[j]);
        }
    }
}

// ---------------------------------------------------------------------------
// K6/K7: C[M,N] = act(A[M,K] @ BT[N,K]^T + bias), m97 structure:
// unpadded 128x32 LDS tiles staged via global_load_lds width=16.
// 4 waves 2x2, each 4x4 16x16x32 bf16 MFMAs.
// Layouts (verified): A-frag m=lane&15,k=quad*8+j; B-frag n=lane&15;
// C/D col=lane&15, row=quad*4+reg.
// ---------------------------------------------------------------------------
template <bool RELU, bool OUT_BF16>
__global__ __launch_bounds__(256) void gemm_bt(
    const bf16_t* __restrict__ A, const bf16_t* __restrict__ BT,
    const float* __restrict__ bias, void* __restrict__ Cout,
    int M, int N, int K) {
    __shared__ bf16_t As[128][32];  // unpadded: required by global_load_lds
    __shared__ bf16_t Bs[128][32];

    const int tid = threadIdx.x;
    const int lane = tid & 63;
    const int w = tid >> 6;
    const int wm = (w & 1) * 64;
    const int wn = (w >> 1) * 64;
    const int lrow = lane & 15;
    const int quad = lane >> 4;
    const int kq = quad * 8;
    const int m0 = blockIdx.x * 128;
    const int n0 = blockIdx.y * 128;

    floatx4 acc[4][4] = {};

    const int nkt = K / 32;
    for (int kt = 0; kt < nkt; ++kt) {
        const int k0 = kt * 32;
        __syncthreads();
#pragma unroll
        for (int it = 0; it < 2; ++it) {
            int slot = it * 256 + tid;
            int row = slot >> 2;
            int cg = (slot & 3) * 8;
            int gm = min(m0 + row, M - 1);  // clamp; garbage rows masked in epilogue
            async16(&A[(size_t)gm * K + k0 + cg], (bf16_t*)As + slot * 8);
            async16(&BT[(size_t)(n0 + row) * K + k0 + cg], (bf16_t*)Bs + slot * 8);
        }
        __syncthreads();  // drains vmcnt before LDS reads

        bf16x8 af[4], bfr[4];
#pragma unroll
        for (int mi = 0; mi < 4; ++mi)
            af[mi] = *reinterpret_cast<const bf16x8*>(&As[wm + mi * 16 + lrow][kq]);
#pragma unroll
        for (int ni = 0; ni < 4; ++ni)
            bfr[ni] = *reinterpret_cast<const bf16x8*>(&Bs[wn + ni * 16 + lrow][kq]);
#pragma unroll
        for (int mi = 0; mi < 4; ++mi)
#pragma unroll
            for (int ni = 0; ni < 4; ++ni)
                acc[mi][ni] = __builtin_amdgcn_mfma_f32_16x16x32_bf16(
                    af[mi], bfr[ni], acc[mi][ni], 0, 0, 0);
    }

#pragma unroll
    for (int ni = 0; ni < 4; ++ni) {
        int gn = n0 + wn + ni * 16 + lrow;
        float bv = bias[gn];
#pragma unroll
        for (int mi = 0; mi < 4; ++mi) {
            int gmb = m0 + wm + mi * 16 + quad * 4;
#pragma unroll
            for (int r = 0; r < 4; ++r) {
                int gm = gmb + r;
                if (gm < M) {
                    float v = acc[mi][ni][r] + bv;
                    if (RELU) v = fmaxf(v, 0.0f);
                    if (OUT_BF16)
                        ((bf16_t*)Cout)[(size_t)gm * N + gn] = to_bf16(v);
                    else
                        ((float*)Cout)[(size_t)gm * N + gn] = v;
                }
            }
        }
    }
}

// ---------------------------------------------------------------------------
extern "C" void kernel_launch(void* const* d_in, const int* in_sizes, int n_in,
                              void* d_out, int out_size, void* d_ws, size_t ws_size,
                              hipStream_t stream) {
    const float* node = (const float*)d_in[0];
    const int* eidx = (const int*)d_in[1];
    const float* ef = (const float*)d_in[2];
    const float* W1 = (const float*)d_in[3];
    const float* b1 = (const float*)d_in[4];
    const float* W2 = (const float*)d_in[5];
    const float* b2 = (const float*)d_in[6];
    float* out = (float*)d_out;

    char* ws = (char*)d_ws;
    int* counts = (int*)ws;                               //   200,000 B
    int* offsets = (int*)(ws + 200000);                   //   200,004 B
    int* cursor = (int*)(ws + 400016);                    //   200,000 B
    int* sorted = (int*)(ws + 600016);                    // 3,200,000 B
    int* local_excl = (int*)(ws + 3800016);               //   200,000 B
    int* blocksums = (int*)(ws + 4000016);                //       784 B
    int* scanned = (int*)(ws + 4000800);                  //       784 B
    bf16_t* combined = (bf16_t*)(ws + 4001600);           // 32,000,000 B (16-aligned)
    bf16_t* h = (bf16_t*)(ws + 36001600);                 // 51,200,000 B (16-aligned)
    bf16_t* W1T = (bf16_t*)(ws + 87201600);               //   327,680 B
    bf16_t* W2T = (bf16_t*)(ws + 87529280);               //   262,144 B

    hipMemsetAsync(counts, 0, 200000, stream);  // ws re-poisoned 0xAA each call

    hist_counts<<<(N_EDGES + 255) / 256, 256, 0, stream>>>(eidx, counts);
    scan_blocks<<<SCAN_BLOCKS, 256, 0, stream>>>(counts, local_excl, blocksums);
    scan_sums<<<1, 256, 0, stream>>>(blocksums, scanned, offsets);
    add_base<<<SCAN_BLOCKS, 256, 0, stream>>>(local_excl, scanned, offsets, cursor);
    scatter_ids<<<(N_EDGES + 255) / 256, 256, 0, stream>>>(eidx, cursor, sorted);
    gather_combined<<<(N_NODES * 64 + 255) / 256, 256, 0, stream>>>(
        ef, sorted, offsets, node, combined);

    convert_weights<<<(IN_DIM * HIDDEN + HIDDEN * OUT_DIM + 255) / 256, 256, 0, stream>>>(
        W1, W2, W1T, W2T);

    // h = relu(combined @ W1 + b1)   [50000,512] bf16
    gemm_bt<true, true><<<dim3((N_NODES + 127) / 128, HIDDEN / 128), 256, 0, stream>>>(
        combined, W1T, b1, (void*)h, N_NODES, HIDDEN, IN_DIM);

    // out = h @ W2 + b2              [50000,256] f32
    gemm_bt<false, false><<<dim3((N_NODES + 127) / 128, OUT_DIM / 128), 256, 0, stream>>>(
        h, W2T, b2, (void*)out, N_NODES, OUT_DIM, HIDDEN);
}

// Round 4
// 553.943 us; speedup vs baseline: 1.2854x; 1.0460x over previous
//
#include <hip/hip_runtime.h>
#include <hip/hip_bf16.h>

#define N_NODES 50000
#define N_EDGES 800000
#define NODE_DIM 256
#define EDGE_DIM 64
#define HIDDEN 512
#define OUT_DIM 256
#define IN_DIM 320   // EDGE_DIM + NODE_DIM
#define SCAN_BLOCKS ((N_NODES + 255) / 256)  // 196

typedef __bf16 bf16_t;
typedef bf16_t bf16x8 __attribute__((ext_vector_type(8)));
typedef bf16_t bf16x4 __attribute__((ext_vector_type(4)));
typedef float floatx4 __attribute__((ext_vector_type(4)));

__device__ inline bf16_t to_bf16(float f) {
    __hip_bfloat16 h = __float2bfloat16(f);
    bf16_t b;
    __builtin_memcpy(&b, &h, 2);
    return b;
}

// async 16B global -> LDS (wave-uniform LDS base + lane*16 pattern required)
__device__ inline void async16(const void* g, void* l) {
    __builtin_amdgcn_global_load_lds(
        (const __attribute__((address_space(1))) unsigned int*)g,
        (__attribute__((address_space(3))) unsigned int*)l, 16, 0, 0);
}

// ---------------------------------------------------------------------------
// K1: histogram of target indices (int atomics)
// ---------------------------------------------------------------------------
__global__ __launch_bounds__(256) void hist_counts(
    const int* __restrict__ eidx, int* __restrict__ counts) {
    int e = blockIdx.x * 256 + threadIdx.x;
    if (e >= N_EDGES) return;
    int t = min(max(eidx[N_EDGES + e], 0), N_NODES - 1);
    atomicAdd(&counts[t], 1);
}

// ---------------------------------------------------------------------------
// K2a: per-block exclusive scan (256 elems/block), emit block totals
// ---------------------------------------------------------------------------
__global__ __launch_bounds__(256) void scan_blocks(
    const int* __restrict__ counts, int* __restrict__ local_excl,
    int* __restrict__ blocksums) {
    __shared__ int s[256];
    int t = threadIdx.x;
    int idx = blockIdx.x * 256 + t;
    int v = (idx < N_NODES) ? counts[idx] : 0;
    s[t] = v;
    __syncthreads();
#pragma unroll
    for (int off = 1; off < 256; off <<= 1) {
        int u = (t >= off) ? s[t - off] : 0;
        __syncthreads();
        s[t] += u;
        __syncthreads();
    }
    if (idx < N_NODES) local_excl[idx] = s[t] - v;  // exclusive
    if (t == 255) blocksums[blockIdx.x] = s[255];
}

// ---------------------------------------------------------------------------
// K2b: scan the block totals (196 elems, single block, one elem/thread)
// ---------------------------------------------------------------------------
__global__ __launch_bounds__(256) void scan_sums(
    const int* __restrict__ blocksums, int* __restrict__ scanned,
    int* __restrict__ offsets) {
    __shared__ int s[256];
    int t = threadIdx.x;
    int v = (t < SCAN_BLOCKS) ? blocksums[t] : 0;
    s[t] = v;
    __syncthreads();
#pragma unroll
    for (int off = 1; off < 256; off <<= 1) {
        int u = (t >= off) ? s[t - off] : 0;
        __syncthreads();
        s[t] += u;
        __syncthreads();
    }
    if (t < SCAN_BLOCKS) scanned[t] = s[t] - v;  // exclusive
    if (t == 255) offsets[N_NODES] = s[255];     // total = N_EDGES
}

// ---------------------------------------------------------------------------
// K2c: offsets[i] = local_excl[i] + scanned[block]; cursor copy
// ---------------------------------------------------------------------------
__global__ __launch_bounds__(256) void add_base(
    const int* __restrict__ local_excl, const int* __restrict__ scanned,
    int* __restrict__ offsets, int* __restrict__ cursor) {
    int idx = blockIdx.x * 256 + threadIdx.x;
    if (idx >= N_NODES) return;
    int o = local_excl[idx] + scanned[blockIdx.x];
    offsets[idx] = o;
    cursor[idx] = o;
}

// ---------------------------------------------------------------------------
// K3: counting-sort pass — place edge ids into per-node contiguous ranges
// ---------------------------------------------------------------------------
__global__ __launch_bounds__(256) void scatter_ids(
    const int* __restrict__ eidx, int* __restrict__ cursor,
    int* __restrict__ sorted) {
    int e = blockIdx.x * 256 + threadIdx.x;
    if (e >= N_EDGES) return;
    int t = min(max(eidx[N_EDGES + e], 0), N_NODES - 1);
    int pos = atomicAdd(&cursor[t], 1);
    sorted[pos] = e;
}

// ---------------------------------------------------------------------------
// K4: gather + mean + concat + bf16 cast -> combined[N, 320]
// One wave per node. 4 edge slots x 16 float4-chunks: each iteration loads
// 4 full edge rows (16 B/lane). Indices preloaded once and shfl-broadcast,
// so the only dependent op in the loop is the row load itself.
// ---------------------------------------------------------------------------
__global__ __launch_bounds__(256) void gather_combined(
    const float* __restrict__ ef, const int* __restrict__ sorted,
    const int* __restrict__ offsets, const float* __restrict__ node,
    bf16_t* __restrict__ combined) {
    int wave = (blockIdx.x * 256 + threadIdx.x) >> 6;
    int lane = threadIdx.x & 63;
    if (wave >= N_NODES) return;
    const int slot = lane >> 4;   // 0..3 : edge slot
    const int g4 = lane & 15;     // float4 chunk within 64-dim row

    int beg = offsets[wave], end = offsets[wave + 1];
    int deg = end - beg;

    // preload up to 64 indices (one coalesced load)
    int myidx = (lane < deg) ? sorted[beg + lane] : -1;

    floatx4 acc = {0.f, 0.f, 0.f, 0.f};
    int nfull = min(deg, 64);
    for (int j = 0; j < nfull; j += 4) {
        int eid = __shfl(myidx, j + slot);
        if (j + slot < nfull) {
            floatx4 v = *reinterpret_cast<const floatx4*>(
                &ef[(size_t)eid * EDGE_DIM + g4 * 4]);
            acc += v;
        }
    }
    // rare tail: deg > 64
    for (int j = 64; j < deg; j += 4) {
        int js = j + slot;
        if (js < deg) {
            int eid = sorted[beg + js];
            floatx4 v = *reinterpret_cast<const floatx4*>(
                &ef[(size_t)eid * EDGE_DIM + g4 * 4]);
            acc += v;
        }
    }

    // reduce across the 4 slots (xor 16, 32) -> every lane has full sum
#pragma unroll
    for (int m = 16; m <= 32; m <<= 1) {
        acc[0] += __shfl_xor(acc[0], m);
        acc[1] += __shfl_xor(acc[1], m);
        acc[2] += __shfl_xor(acc[2], m);
        acc[3] += __shfl_xor(acc[3], m);
    }

    float inv = 1.0f / (float)max(deg, 1);
    size_t cb = (size_t)wave * IN_DIM;
    if (slot == 0) {  // lanes 0..15 write the 64 edge dims (8 B each)
        bf16x4 o;
        o[0] = to_bf16(acc[0] * inv);
        o[1] = to_bf16(acc[1] * inv);
        o[2] = to_bf16(acc[2] * inv);
        o[3] = to_bf16(acc[3] * inv);
        *reinterpret_cast<bf16x4*>(&combined[cb + g4 * 4]) = o;
    }
    // node features: 256 floats, lane loads float4, stores 4 bf16 (8 B)
    floatx4 nv = *reinterpret_cast<const floatx4*>(
        &node[(size_t)wave * NODE_DIM + lane * 4]);
    bf16x4 no;
    no[0] = to_bf16(nv[0]);
    no[1] = to_bf16(nv[1]);
    no[2] = to_bf16(nv[2]);
    no[3] = to_bf16(nv[3]);
    *reinterpret_cast<bf16x4*>(&combined[cb + EDGE_DIM + lane * 4]) = no;
}

// ---------------------------------------------------------------------------
// K5: weights -> transposed bf16
// ---------------------------------------------------------------------------
__global__ __launch_bounds__(256) void convert_weights(
    const float* __restrict__ W1, const float* __restrict__ W2,
    bf16_t* __restrict__ W1T, bf16_t* __restrict__ W2T) {
    int idx = blockIdx.x * 256 + threadIdx.x;
    if (idx < IN_DIM * HIDDEN) {
        int k = idx / HIDDEN, n = idx - k * HIDDEN;
        W1T[(size_t)n * IN_DIM + k] = to_bf16(W1[idx]);
    } else {
        int j = idx - IN_DIM * HIDDEN;
        if (j < HIDDEN * OUT_DIM) {
            int k = j / OUT_DIM, n = j - k * OUT_DIM;
            W2T[(size_t)n * HIDDEN + k] = to_bf16(W2[j]);
        }
    }
}

// ---------------------------------------------------------------------------
// K6/K7: C[M,N] = act(A[M,K] @ BT[N,K]^T + bias), m97 structure:
// unpadded 128x32 LDS tiles staged via global_load_lds width=16.
// 4 waves 2x2, each 4x4 16x16x32 bf16 MFMAs.
// ---------------------------------------------------------------------------
template <bool RELU, bool OUT_BF16>
__global__ __launch_bounds__(256) void gemm_bt(
    const bf16_t* __restrict__ A, const bf16_t* __restrict__ BT,
    const float* __restrict__ bias, void* __restrict__ Cout,
    int M, int N, int K) {
    __shared__ bf16_t As[128][32];  // unpadded: required by global_load_lds
    __shared__ bf16_t Bs[128][32];

    const int tid = threadIdx.x;
    const int lane = tid & 63;
    const int w = tid >> 6;
    const int wm = (w & 1) * 64;
    const int wn = (w >> 1) * 64;
    const int lrow = lane & 15;
    const int quad = lane >> 4;
    const int kq = quad * 8;
    const int m0 = blockIdx.x * 128;
    const int n0 = blockIdx.y * 128;

    floatx4 acc[4][4] = {};

    const int nkt = K / 32;
    for (int kt = 0; kt < nkt; ++kt) {
        const int k0 = kt * 32;
        __syncthreads();
#pragma unroll
        for (int it = 0; it < 2; ++it) {
            int slot = it * 256 + tid;
            int row = slot >> 2;
            int cg = (slot & 3) * 8;
            int gm = min(m0 + row, M - 1);  // clamp; garbage rows masked in epilogue
            async16(&A[(size_t)gm * K + k0 + cg], (bf16_t*)As + slot * 8);
            async16(&BT[(size_t)(n0 + row) * K + k0 + cg], (bf16_t*)Bs + slot * 8);
        }
        __syncthreads();  // drains vmcnt before LDS reads

        bf16x8 af[4], bfr[4];
#pragma unroll
        for (int mi = 0; mi < 4; ++mi)
            af[mi] = *reinterpret_cast<const bf16x8*>(&As[wm + mi * 16 + lrow][kq]);
#pragma unroll
        for (int ni = 0; ni < 4; ++ni)
            bfr[ni] = *reinterpret_cast<const bf16x8*>(&Bs[wn + ni * 16 + lrow][kq]);
#pragma unroll
        for (int mi = 0; mi < 4; ++mi)
#pragma unroll
            for (int ni = 0; ni < 4; ++ni)
                acc[mi][ni] = __builtin_amdgcn_mfma_f32_16x16x32_bf16(
                    af[mi], bfr[ni], acc[mi][ni], 0, 0, 0);
    }

#pragma unroll
    for (int ni = 0; ni < 4; ++ni) {
        int gn = n0 + wn + ni * 16 + lrow;
        float bv = bias[gn];
#pragma unroll
        for (int mi = 0; mi < 4; ++mi) {
            int gmb = m0 + wm + mi * 16 + quad * 4;
#pragma unroll
            for (int r = 0; r < 4; ++r) {
                int gm = gmb + r;
                if (gm < M) {
                    float v = acc[mi][ni][r] + bv;
                    if (RELU) v = fmaxf(v, 0.0f);
                    if (OUT_BF16)
                        ((bf16_t*)Cout)[(size_t)gm * N + gn] = to_bf16(v);
                    else
                        ((float*)Cout)[(size_t)gm * N + gn] = v;
                }
            }
        }
    }
}

// ---------------------------------------------------------------------------
extern "C" void kernel_launch(void* const* d_in, const int* in_sizes, int n_in,
                              void* d_out, int out_size, void* d_ws, size_t ws_size,
                              hipStream_t stream) {
    const float* node = (const float*)d_in[0];
    const int* eidx = (const int*)d_in[1];
    const float* ef = (const float*)d_in[2];
    const float* W1 = (const float*)d_in[3];
    const float* b1 = (const float*)d_in[4];
    const float* W2 = (const float*)d_in[5];
    const float* b2 = (const float*)d_in[6];
    float* out = (float*)d_out;

    char* ws = (char*)d_ws;
    int* counts = (int*)ws;                               //   200,000 B
    int* offsets = (int*)(ws + 200000);                   //   200,004 B
    int* cursor = (int*)(ws + 400016);                    //   200,000 B
    int* sorted = (int*)(ws + 600016);                    // 3,200,000 B
    int* local_excl = (int*)(ws + 3800016);               //   200,000 B
    int* blocksums = (int*)(ws + 4000016);                //       784 B
    int* scanned = (int*)(ws + 4000800);                  //       784 B
    bf16_t* combined = (bf16_t*)(ws + 4001600);           // 32,000,000 B (16-aligned)
    bf16_t* h = (bf16_t*)(ws + 36001600);                 // 51,200,000 B (16-aligned)
    bf16_t* W1T = (bf16_t*)(ws + 87201600);               //   327,680 B
    bf16_t* W2T = (bf16_t*)(ws + 87529280);               //   262,144 B

    hipMemsetAsync(counts, 0, 200000, stream);  // ws re-poisoned 0xAA each call

    hist_counts<<<(N_EDGES + 255) / 256, 256, 0, stream>>>(eidx, counts);
    scan_blocks<<<SCAN_BLOCKS, 256, 0, stream>>>(counts, local_excl, blocksums);
    scan_sums<<<1, 256, 0, stream>>>(blocksums, scanned, offsets);
    add_base<<<SCAN_BLOCKS, 256, 0, stream>>>(local_excl, scanned, offsets, cursor);
    scatter_ids<<<(N_EDGES + 255) / 256, 256, 0, stream>>>(eidx, cursor, sorted);
    gather_combined<<<(N_NODES * 64 + 255) / 256, 256, 0, stream>>>(
        ef, sorted, offsets, node, combined);

    convert_weights<<<(IN_DIM * HIDDEN + HIDDEN * OUT_DIM + 255) / 256, 256, 0, stream>>>(
        W1, W2, W1T, W2T);

    // h = relu(combined @ W1 + b1)   [50000,512] bf16
    gemm_bt<true, true><<<dim3((N_NODES + 127) / 128, HIDDEN / 128), 256, 0, stream>>>(
        combined, W1T, b1, (void*)h, N_NODES, HIDDEN, IN_DIM);

    // out = h @ W2 + b2              [50000,256] f32
    gemm_bt<false, false><<<dim3((N_NODES + 127) / 128, OUT_DIM / 128), 256, 0, stream>>>(
        h, W2T, b2, (void*)out, N_NODES, OUT_DIM, HIDDEN);
}